// Round 10
// baseline (2041.786 us; speedup 1.0000x reference)
//
#include <hip/hip_runtime.h>

typedef __attribute__((ext_vector_type(4))) float f32x4;
typedef __attribute__((ext_vector_type(8))) short s16x8;
typedef __attribute__((ext_vector_type(4))) unsigned short u16x4;
typedef __attribute__((ext_vector_type(8))) unsigned short u16x8;
typedef unsigned short u16;

// ---------- bf16 helpers (RNE) ----------
__device__ inline u16 f2bf(float x) {
  unsigned u = __float_as_uint(x);
  return (u16)((u + 0x7fffu + ((u >> 16) & 1u)) >> 16);
}
__device__ inline float bf2f(u16 h) {
  return __uint_as_float(((unsigned)h) << 16);
}

__device__ inline void glds16(const void* g, void* l) {
  __builtin_amdgcn_global_load_lds((const __attribute__((address_space(1))) void*)g,
                                   (__attribute__((address_space(3))) void*)l, 16, 0, 0);
}

// ---------- GEMM: C[M,N] = A[M,K] (bf16) @ W[N,K]^T ----------
// BM=32*FM, BN=32*FN, BK=128; 4 waves (2x2); A via global_load_lds w16; linear LDS +
// source-side XOR swizzle over 16 k-subchunks (key=row&15), same involution on read.
// WF32=1: W is fp32 in global, reg-staged (2x f32x4 -> cvt -> ds_write_b128) into the
//         IDENTICAL swizzled LDS layout (lane*8 slot == global_load_lds lane*16B).
// MODE: 0=f32 out, 1=f32+bias, 2=bf16 out, 3=dt epilogue (bf16 dt + f32 aux), 4=GLU bf16.
template<int FM, int FN, int NWB, int MODE, int WF32>
__global__ __launch_bounds__(256)
void gemm_bf(const u16* __restrict__ A, int lda,
             const void* __restrict__ W0v, const void* __restrict__ W1v, int ldw,
             void* __restrict__ Cv, int ldc, int K,
             const float* __restrict__ bias, float* __restrict__ aux) {
  constexpr int BM = 32 * FM, BN = 32 * FN, BK = 128;
  constexpr int CA = BM / 4, CW = BN / 4, TOT = CA + NWB * CW;
  __shared__ alignas(16) u16 lA[BM * BK];
  __shared__ alignas(16) u16 lW[NWB][BN * BK];
  const int tid = threadIdx.x, wave = tid >> 6, lane = tid & 63;
  const int m0 = blockIdx.y * BM, n0 = blockIdx.x * BN;
  const int wr = (wave >> 1) * (16 * FM), wc = (wave & 1) * (16 * FN);
  const int fr = lane & 15, fq = lane >> 4;
  const int rin = lane >> 4, c16 = lane & 15;
  f32x4 acc[FM][FN] = {};
  f32x4 acc2[FM][FN] = {};
  for (int k0 = 0; k0 < K; k0 += BK) {
    __syncthreads();
    #pragma unroll
    for (int c = 0; c < TOT; ++c) {
      if ((c & 3) != wave) continue;
      if (c < CA) {
        int row = c * 4 + rin;
        glds16(A + (size_t)(m0 + row) * lda + k0 + ((c16 ^ (row & 15)) * 8), &lA[c * 512]);
      } else {
        int wi = (c - CA) / CW, ch = (c - CA) % CW;
        int row = ch * 4 + rin;
        int kc = (c16 ^ (row & 15)) * 8;
        if (WF32) {
          const float* Wf = (wi == 0) ? (const float*)W0v : (const float*)W1v;
          const float* src = Wf + (size_t)(n0 + row) * ldw + k0 + kc;
          f32x4 v0 = *reinterpret_cast<const f32x4*>(src);
          f32x4 v1 = *reinterpret_cast<const f32x4*>(src + 4);
          u16x8 hv;
          #pragma unroll
          for (int j = 0; j < 4; ++j) { hv[j] = f2bf(v0[j]); hv[4 + j] = f2bf(v1[j]); }
          *reinterpret_cast<u16x8*>(&lW[wi][ch * 512 + lane * 8]) = hv;
        } else {
          const u16* Wb = (wi == 0) ? (const u16*)W0v : (const u16*)W1v;
          glds16(Wb + (size_t)(n0 + row) * ldw + k0 + kc, &lW[wi][ch * 512]);
        }
      }
    }
    __syncthreads();
    #pragma unroll
    for (int s = 0; s < 4; ++s) {
      const int u = s * 4 + fq;
      s16x8 af[FM];
      #pragma unroll
      for (int mi = 0; mi < FM; ++mi) {
        int r = wr + mi * 16 + fr;
        af[mi] = *reinterpret_cast<const s16x8*>(&lA[r * 128 + ((u ^ (r & 15)) * 8)]);
      }
      #pragma unroll
      for (int wi = 0; wi < NWB; ++wi) {
        #pragma unroll
        for (int ni = 0; ni < FN; ++ni) {
          int r = wc + ni * 16 + fr;
          s16x8 bfr = *reinterpret_cast<const s16x8*>(&lW[wi][r * 128 + ((u ^ (r & 15)) * 8)]);
          #pragma unroll
          for (int mi = 0; mi < FM; ++mi) {
            if (MODE == 4 && wi == 1)
              acc2[mi][ni] = __builtin_amdgcn_mfma_f32_16x16x32_bf16(af[mi], bfr, acc2[mi][ni], 0, 0, 0);
            else
              acc[mi][ni] = __builtin_amdgcn_mfma_f32_16x16x32_bf16(af[mi], bfr, acc[mi][ni], 0, 0, 0);
          }
        }
      }
    }
  }
  #pragma unroll
  for (int mi = 0; mi < FM; ++mi)
    #pragma unroll
    for (int ni = 0; ni < FN; ++ni) {
      int gm = m0 + wr + mi * 16 + fq * 4;
      int gn = n0 + wc + ni * 16 + fr;
      if (MODE == 2) {
        u16* Cb = (u16*)Cv;
        #pragma unroll
        for (int r = 0; r < 4; ++r)
          Cb[(size_t)(gm + r) * ldc + gn] = f2bf(acc[mi][ni][r]);
      } else if (MODE == 4) {
        u16* Cb = (u16*)Cv;
        #pragma unroll
        for (int r = 0; r < 4; ++r) {
          float y = acc[mi][ni][r], g = acc2[mi][ni][r];
          Cb[(size_t)(gm + r) * ldc + gn] = f2bf(y * (g / (1.f + __expf(-g))));
        }
      } else if (MODE == 3) {
        u16* Cb = (u16*)Cv;
        if (gn < 1024) {
          float badd = bias[gn];
          #pragma unroll
          for (int r = 0; r < 4; ++r) {
            float s = acc[mi][ni][r] + badd;
            s = (s > 20.f) ? s : log1pf(__expf(s));
            Cb[(size_t)(gm + r) * ldc + gn] = f2bf(s);
          }
        } else if (gn < 1056) {
          #pragma unroll
          for (int r = 0; r < 4; ++r)
            aux[(size_t)(gm + r) * 32 + (gn - 1024)] = acc[mi][ni][r];
        }
      } else {
        float* C = (float*)Cv;
        float badd = (MODE == 1) ? bias[gn] : 0.f;
        #pragma unroll
        for (int r = 0; r < 4; ++r)
          C[(size_t)(gm + r) * ldc + gn] = acc[mi][ni][r] + badd;
      }
    }
}

// ---------- prep: Mext (fused dt/BC weight, bf16) FIRST, then x -> bf16 ----------
// blocks [0,1632): Mext, 136/layer: lb<128 -> 8 dt-rows/block (dtw@xpw_dt);
//   lb in [128,136) -> rows 1024..1087 (BC rows <1056, zero pad above).
// blocks [1632,1760): x -> bf16 (262144 elems, 2048/block).
__global__ void k_prep(const float* __restrict__ x,
                       const float* __restrict__ dtw_a, const float* __restrict__ xpw_a,
                       u16* __restrict__ xb, u16* __restrict__ mall) {
  int blk = blockIdx.x, tid = threadIdx.x;
  if (blk < 1632) {
    int layer = blk / 136, lb = blk % 136;
    u16* mh = mall + (size_t)layer * 1114112;
    const float* xpw = xpw_a + (size_t)layer * 65536;
    if (lb < 128) {
      const float* dtw = dtw_a + (size_t)layer * 32768;
      int o0 = lb * 8;
      __shared__ float lw[8][32];
      {
        int row = tid >> 5, r = tid & 31;
        lw[row][r] = dtw[(o0 + row) * 32 + r];
      }
      __syncthreads();
      f32x4 a[8] = {};
      for (int r = 0; r < 32; ++r) {
        f32x4 xv = *reinterpret_cast<const f32x4*>(xpw + (size_t)r * 1024 + tid * 4);
        #pragma unroll
        for (int row = 0; row < 8; ++row) {
          float wv = lw[row][r];
          #pragma unroll
          for (int j = 0; j < 4; ++j) a[row][j] += wv * xv[j];
        }
      }
      #pragma unroll
      for (int row = 0; row < 8; ++row) {
        u16x4 hv;
        #pragma unroll
        for (int j = 0; j < 4; ++j) hv[j] = f2bf(a[row][j]);
        *reinterpret_cast<u16x4*>(mh + (size_t)(o0 + row) * 1024 + tid * 4) = hv;
      }
    } else {
      int o0 = 1024 + (lb - 128) * 8;
      #pragma unroll
      for (int row = 0; row < 8; ++row) {
        int o = o0 + row;
        u16x4 hv = {0, 0, 0, 0};
        if (o < 1056) {
          f32x4 xv = *reinterpret_cast<const f32x4*>(xpw + (size_t)(o - 1024 + 32) * 1024 + tid * 4);
          #pragma unroll
          for (int j = 0; j < 4; ++j) hv[j] = f2bf(xv[j]);
        }
        *reinterpret_cast<u16x4*>(mh + (size_t)o * 1024 + tid * 4) = hv;
      }
    }
  } else {
    size_t base = (size_t)(blk - 1632) * 2048;
    f32x4 v0 = *reinterpret_cast<const f32x4*>(x + base + tid * 4);
    f32x4 v1 = *reinterpret_cast<const f32x4*>(x + base + 1024 + tid * 4);
    u16x4 h0, h1;
    #pragma unroll
    for (int j = 0; j < 4; ++j) { h0[j] = f2bf(v0[j]); h1[j] = f2bf(v1[j]); }
    *reinterpret_cast<u16x4*>(xb + base + tid * 4) = h0;
    *reinterpret_cast<u16x4*>(xb + base + 1024 + tid * 4) = h1;
  }
}

// ---------- residual add + rmsnorm; zr=1 treats resid as zero (layer 0) ----------
__global__ void k_addnorm(float* __restrict__ r, const float* __restrict__ h,
                          const float* __restrict__ w, u16* __restrict__ ob, int zr) {
  int t = blockIdx.x, tid = threadIdx.x;
  size_t base = (size_t)t * 512;
  float h0 = h[base + tid], h1 = h[base + 256 + tid];
  float s0 = zr ? h0 : (r[base + tid] + h0);
  float s1 = zr ? h1 : (r[base + 256 + tid] + h1);
  float ss = s0 * s0 + s1 * s1;
  for (int m = 32; m; m >>= 1) ss += __shfl_xor(ss, m);
  __shared__ float red[4];
  if ((tid & 63) == 0) red[tid >> 6] = ss;
  __syncthreads();
  float tot = red[0] + red[1] + red[2] + red[3];
  float sc = rsqrtf(tot * (1.f / 512.f) + 1e-5f);
  r[base + tid] = s0;
  r[base + 256 + tid] = s1;
  ob[base + tid] = f2bf(s0 * sc * w[tid]);
  ob[base + 256 + tid] = f2bf(s1 * sc * w[tid + 256]);
}

// ---------- causal depthwise conv (4 taps) + silu; bf16 in, bf16 out ----------
__global__ void k_conv(const u16* __restrict__ xzb, const float* __restrict__ cw,
                       const float* __restrict__ cb, u16* __restrict__ xcb) {
  int idx = blockIdx.x * 256 + threadIdx.x;
  int t = idx >> 8, q4 = (idx & 255) * 4;
  int l = t & 511;
  f32x4 w0 = *reinterpret_cast<const f32x4*>(cw + (q4 + 0) * 4);
  f32x4 w1 = *reinterpret_cast<const f32x4*>(cw + (q4 + 1) * 4);
  f32x4 w2 = *reinterpret_cast<const f32x4*>(cw + (q4 + 2) * 4);
  f32x4 w3 = *reinterpret_cast<const f32x4*>(cw + (q4 + 3) * 4);
  f32x4 a = *reinterpret_cast<const f32x4*>(cb + q4);
  #pragma unroll
  for (int j = 0; j < 4; ++j) {
    int lj = l - 3 + j;
    if (lj >= 0) {
      u16x4 v = *reinterpret_cast<const u16x4*>(xzb + (size_t)(t - 3 + j) * 2048 + q4);
      a[0] += w0[j] * bf2f(v[0]);
      a[1] += w1[j] * bf2f(v[1]);
      a[2] += w2[j] * bf2f(v[2]);
      a[3] += w3[j] * bf2f(v[3]);
    }
  }
  u16x4 ob;
  #pragma unroll
  for (int j = 0; j < 4; ++j)
    ob[j] = f2bf(a[j] / (1.f + __expf(-a[j])));
  *reinterpret_cast<u16x4*>(xcb + (size_t)t * 1024 + q4) = ob;
}

// ---------- scan pass 1 ----------
__global__ __launch_bounds__(256) void k_scan1(
    const u16* __restrict__ dtb, const u16* __restrict__ xcb,
    const float* __restrict__ xdb, const float* __restrict__ alog,
    float* __restrict__ sP, float* __restrict__ sH) {
  int bid = blockIdx.x;
  int b = bid >> 7, dg = (bid >> 3) & 15, c = bid & 7;
  int tid = threadIdx.x, dl = tid >> 2, sq = tid & 3;
  int d = dg * 64 + dl;
  int t0 = b * 512 + c * 64;
  __shared__ u16 ldt[16][64], lxc[16][64];
  __shared__ float lB[16][16];
  f32x4 al = *reinterpret_cast<const f32x4*>(alog + (size_t)d * 16 + sq * 4);
  float A[4], h[4] = {}, P[4] = {1.f, 1.f, 1.f, 1.f};
  #pragma unroll
  for (int j = 0; j < 4; ++j) A[j] = -__expf(al[j]);
  for (int tile = 0; tile < 4; ++tile) {
    int tt = t0 + tile * 16;
    __syncthreads();
    {
      int row = tid >> 4, f4 = (tid & 15) * 4;
      *reinterpret_cast<u16x4*>(&ldt[row][f4]) =
          *reinterpret_cast<const u16x4*>(dtb + (size_t)(tt + row) * 1024 + dg * 64 + f4);
      *reinterpret_cast<u16x4*>(&lxc[row][f4]) =
          *reinterpret_cast<const u16x4*>(xcb + (size_t)(tt + row) * 1024 + dg * 64 + f4);
    }
    if (tid < 64) {
      int row = tid >> 2, f4 = (tid & 3) * 4;
      *reinterpret_cast<f32x4*>(&lB[row][f4]) =
          *reinterpret_cast<const f32x4*>(xdb + (size_t)(tt + row) * 32 + f4);
    }
    __syncthreads();
    for (int lr = 0; lr < 16; ++lr) {
      float dtv = bf2f(ldt[lr][dl]);
      float dtx = dtv * bf2f(lxc[lr][dl]);
      f32x4 Bv = *reinterpret_cast<const f32x4*>(&lB[lr][sq * 4]);
      #pragma unroll
      for (int j = 0; j < 4; ++j) {
        float e = __expf(dtv * A[j]);
        h[j] = h[j] * e + dtx * Bv[j];
        P[j] *= e;
      }
    }
  }
  size_t base = ((size_t)(c * 4 + b) * 1024 + d) * 16 + sq * 4;
  *reinterpret_cast<f32x4*>(sP + base) = (f32x4){P[0], P[1], P[2], P[3]};
  *reinterpret_cast<f32x4*>(sH + base) = (f32x4){h[0], h[1], h[2], h[3]};
}

// ---------- scan pass 2 ----------
__global__ __launch_bounds__(256) void k_scan3(
    const u16* __restrict__ dtb, const u16* __restrict__ xcb,
    const float* __restrict__ xdb, const float* __restrict__ alog,
    const float* __restrict__ sP, const float* __restrict__ sH,
    const u16* __restrict__ xzb, const float* __restrict__ Dw,
    u16* __restrict__ ygb) {
  int bid = blockIdx.x;
  int b = bid >> 7, dg = (bid >> 3) & 15, c = bid & 7;
  int tid = threadIdx.x, dl = tid >> 2, sq = tid & 3;
  int d = dg * 64 + dl;
  int t0 = b * 512 + c * 64;
  __shared__ u16 ldt[16][64], lxc[16][64];
  __shared__ float lB[16][16], lC[16][16], ly[16][64];
  f32x4 al = *reinterpret_cast<const f32x4*>(alog + (size_t)d * 16 + sq * 4);
  float A[4], h[4] = {};
  #pragma unroll
  for (int j = 0; j < 4; ++j) A[j] = -__expf(al[j]);
  {
    size_t base = ((size_t)b * 1024 + d) * 16 + sq * 4;
    for (int cc = 0; cc < c; ++cc) {
      f32x4 Pp = *reinterpret_cast<const f32x4*>(sP + (size_t)cc * 65536 + base);
      f32x4 Hh = *reinterpret_cast<const f32x4*>(sH + (size_t)cc * 65536 + base);
      #pragma unroll
      for (int j = 0; j < 4; ++j) h[j] = Pp[j] * h[j] + Hh[j];
    }
  }
  for (int tile = 0; tile < 4; ++tile) {
    int tt = t0 + tile * 16;
    __syncthreads();
    {
      int row = tid >> 4, f4 = (tid & 15) * 4;
      *reinterpret_cast<u16x4*>(&ldt[row][f4]) =
          *reinterpret_cast<const u16x4*>(dtb + (size_t)(tt + row) * 1024 + dg * 64 + f4);
      *reinterpret_cast<u16x4*>(&lxc[row][f4]) =
          *reinterpret_cast<const u16x4*>(xcb + (size_t)(tt + row) * 1024 + dg * 64 + f4);
    }
    if (tid < 64) {
      int row = tid >> 2, f4 = (tid & 3) * 4;
      *reinterpret_cast<f32x4*>(&lB[row][f4]) =
          *reinterpret_cast<const f32x4*>(xdb + (size_t)(tt + row) * 32 + f4);
    } else if (tid < 128) {
      int t2 = tid - 64;
      int row = t2 >> 2, f4 = (t2 & 3) * 4;
      *reinterpret_cast<f32x4*>(&lC[row][f4]) =
          *reinterpret_cast<const f32x4*>(xdb + (size_t)(tt + row) * 32 + 16 + f4);
    }
    __syncthreads();
    for (int lr = 0; lr < 16; ++lr) {
      float dtv = bf2f(ldt[lr][dl]);
      float dtx = dtv * bf2f(lxc[lr][dl]);
      f32x4 Bv = *reinterpret_cast<const f32x4*>(&lB[lr][sq * 4]);
      f32x4 Cv = *reinterpret_cast<const f32x4*>(&lC[lr][sq * 4]);
      float py = 0.f;
      #pragma unroll
      for (int j = 0; j < 4; ++j) {
        float e = __expf(dtv * A[j]);
        h[j] = h[j] * e + dtx * Bv[j];
        py += h[j] * Cv[j];
      }
      py += __shfl_xor(py, 1);
      py += __shfl_xor(py, 2);
      if (sq == 0) ly[lr][dl] = py;
    }
    __syncthreads();
    {
      int row = tid >> 4, f4 = (tid & 15) * 4;
      f32x4 y4 = *reinterpret_cast<f32x4*>(&ly[row][f4]);
      u16x4 x4 = *reinterpret_cast<u16x4*>(&lxc[row][f4]);
      u16x4 z4 = *reinterpret_cast<const u16x4*>(xzb + (size_t)(tt + row) * 2048 + 1024 + dg * 64 + f4);
      f32x4 D4 = *reinterpret_cast<const f32x4*>(Dw + dg * 64 + f4);
      u16x4 o;
      #pragma unroll
      for (int j = 0; j < 4; ++j) {
        float yv = y4[j] + bf2f(x4[j]) * D4[j];
        float zz = bf2f(z4[j]);
        float g = zz / (1.f + __expf(-zz));
        o[j] = f2bf(yv * g);
      }
      *reinterpret_cast<u16x4*>(ygb + (size_t)(tt + row) * 1024 + dg * 64 + f4) = o;
    }
  }
}

// ---------- mean pool (bf16 in) + head ----------
__global__ void k_pool(const u16* __restrict__ xnb, float* __restrict__ pooled) {
  int b = blockIdx.x >> 1, half = blockIdx.x & 1;
  int tid = threadIdx.x;
  int dm = half * 256 + tid;
  float s = 0.f;
  for (int l = 0; l < 512; ++l)
    s += bf2f(xnb[(size_t)(b * 512 + l) * 512 + dm]);
  pooled[b * 512 + dm] = s * (1.f / 512.f);
}

__global__ void k_head(const float* __restrict__ pooled, const float* __restrict__ hw,
                       const float* __restrict__ hb, float* __restrict__ out) {
  int b = blockIdx.x / 50, c = blockIdx.x % 50;
  int lane = threadIdx.x;
  float s = 0.f;
  #pragma unroll
  for (int q = 0; q < 8; ++q) {
    int dm = q * 64 + lane;
    s += pooled[b * 512 + dm] * hw[(size_t)c * 512 + dm];
  }
  for (int m = 32; m; m >>= 1) s += __shfl_xor(s, m);
  if (lane == 0) out[b * 50 + c] = s + hb[c];
}

// ---------- launch ----------
extern "C" void kernel_launch(void* const* d_in, const int* in_sizes, int n_in,
                              void* d_out, int out_size, void* d_ws, size_t ws_size,
                              hipStream_t stream) {
  (void)in_sizes; (void)n_in; (void)out_size; (void)ws_size;
  const float* x      = (const float*)d_in[0];
  const float* emb_w  = (const float*)d_in[1];
  const float* emb_b  = (const float*)d_in[2];
  const float* inp_w  = (const float*)d_in[3];
  const float* conv_w = (const float*)d_in[4];
  const float* conv_b = (const float*)d_in[5];
  const float* xp_w   = (const float*)d_in[6];
  const float* dt_w   = (const float*)d_in[7];
  const float* dt_b   = (const float*)d_in[8];
  const float* a_log  = (const float*)d_in[9];
  const float* Dw     = (const float*)d_in[10];
  const float* outp_w = (const float*)d_in[11];
  const float* n1_w   = (const float*)d_in[12];
  const float* n2_w   = (const float*)d_in[13];
  const float* fc1_w  = (const float*)d_in[14];
  const float* fc2_w  = (const float*)d_in[15];
  const float* nf_w   = (const float*)d_in[16];
  const float* head_w = (const float*)d_in[17];
  const float* head_b = (const float*)d_in[18];

  float* fp = (float*)d_ws;
  float* resid  = fp;                 // 2048 x 512
  float* hid    = fp + 1048576;
  float* xdb    = fp + 2097152;       // T x 32 (B|C)
  float* sP     = fp + 2162688;       // 8 x 4 x 1024 x 16
  float* sH     = fp + 2686976;
  float* pooled = fp + 3211264;       // 2048
  u16* us  = (u16*)(fp + 3213312);
  u16* xzb  = us;                     // T x 2048
  u16* xb   = us + 4194304;           // 262144
  u16* xnb  = us + 4456448;           // T x 512
  u16* ygb  = us + 5505024;           // T x 1024
  u16* mlb  = us + 7602176;           // T x 2048
  u16* xcb  = us + 11796480;          // T x 1024
  u16* dtb  = us + 13893632;          // T x 1024
  u16* mall = us + 15990784;          // 12 x Mext(1088x1024)

  const size_t MSTRIDE = 1114112;

  k_prep<<<1760, 256, 0, stream>>>(x, dt_w, xp_w, xb, mall);
  gemm_bf<2, 1, 1, 1, 1><<<dim3(16, 32), 256, 0, stream>>>(
      xb, 128, emb_w, nullptr, 128, (void*)hid, 512, 128, emb_b, nullptr);

  for (int i = 0; i < 12; ++i) {
    k_addnorm<<<2048, 256, 0, stream>>>(resid, hid, n1_w + i * 512, xnb, i == 0 ? 1 : 0);
    gemm_bf<4, 2, 1, 2, 1><<<dim3(32, 16), 256, 0, stream>>>(
        xnb, 512, inp_w + (size_t)i * 1048576, nullptr, 512,
        (void*)xzb, 2048, 512, nullptr, nullptr);
    k_conv<<<2048, 256, 0, stream>>>(xzb, conv_w + (size_t)i * 4096, conv_b + i * 1024, xcb);
    gemm_bf<2, 2, 1, 3, 0><<<dim3(17, 32), 256, 0, stream>>>(
        xcb, 1024, mall + (size_t)i * MSTRIDE, nullptr, 1024,
        (void*)dtb, 1024, 1024, dt_b + i * 1024, xdb);
    k_scan1<<<512, 256, 0, stream>>>(dtb, xcb, xdb, a_log + (size_t)i * 16384, sP, sH);
    k_scan3<<<512, 256, 0, stream>>>(dtb, xcb, xdb, a_log + (size_t)i * 16384, sP, sH,
                                     xzb, Dw + i * 1024, ygb);
    gemm_bf<2, 1, 1, 0, 1><<<dim3(16, 32), 256, 0, stream>>>(
        ygb, 1024, outp_w + (size_t)i * 524288, nullptr, 1024,
        (void*)hid, 512, 1024, nullptr, nullptr);
    k_addnorm<<<2048, 256, 0, stream>>>(resid, hid, n2_w + i * 512, xnb, 0);
    gemm_bf<4, 2, 2, 4, 1><<<dim3(32, 16), 256, 0, stream>>>(
        xnb, 512, fc1_w + (size_t)i * 2097152, fc1_w + (size_t)i * 2097152 + 1048576, 512,
        (void*)mlb, 2048, 512, nullptr, nullptr);
    gemm_bf<2, 1, 1, 0, 1><<<dim3(16, 32), 256, 0, stream>>>(
        mlb, 2048, fc2_w + (size_t)i * 1048576, nullptr, 2048,
        (void*)hid, 512, 2048, nullptr, nullptr);
  }

  k_addnorm<<<2048, 256, 0, stream>>>(resid, hid, nf_w, xnb, 0);
  k_pool<<<8, 256, 0, stream>>>(xnb, pooled);
  k_head<<<200, 64, 0, stream>>>(pooled, head_w, head_b, (float*)d_out);
}

// Round 11
// 1665.653 us; speedup vs baseline: 1.2258x; 1.2258x over previous
//
#include <hip/hip_runtime.h>

typedef __attribute__((ext_vector_type(4))) float f32x4;
typedef __attribute__((ext_vector_type(8))) short s16x8;
typedef __attribute__((ext_vector_type(4))) unsigned short u16x4;
typedef unsigned short u16;

// ---------- bf16 helpers (RNE) ----------
__device__ inline u16 f2bf(float x) {
  unsigned u = __float_as_uint(x);
  return (u16)((u + 0x7fffu + ((u >> 16) & 1u)) >> 16);
}
__device__ inline float bf2f(u16 h) {
  return __uint_as_float(((unsigned)h) << 16);
}

__device__ inline void glds16(const void* g, void* l) {
  __builtin_amdgcn_global_load_lds((const __attribute__((address_space(1))) void*)g,
                                   (__attribute__((address_space(3))) void*)l, 16, 0, 0);
}

// ---------- GEMM: C[M,N] = A[M,K] (bf16) @ W[N,K]^T (bf16) ----------
// BM=32*FM, BN=32*FN, BK=128; 4 waves (2x2); global_load_lds w16; linear LDS dest +
// source-side XOR swizzle over 16 k-subchunks (key=row&15), same involution on read.
// MODE: 0=f32 out, 1=f32+bias, 2=bf16 out, 3=dt epilogue (bf16 dt + f32 aux), 4=GLU bf16.
template<int FM, int FN, int NWB, int MODE>
__global__ __launch_bounds__(256)
void gemm_bf(const u16* __restrict__ A, int lda,
             const u16* __restrict__ W0, const u16* __restrict__ W1, int ldw,
             void* __restrict__ Cv, int ldc, int K,
             const float* __restrict__ bias, float* __restrict__ aux) {
  constexpr int BM = 32 * FM, BN = 32 * FN, BK = 128;
  constexpr int CA = BM / 4, CW = BN / 4, TOT = CA + NWB * CW;
  __shared__ alignas(16) u16 lA[BM * BK];
  __shared__ alignas(16) u16 lW[NWB][BN * BK];
  const int tid = threadIdx.x, wave = tid >> 6, lane = tid & 63;
  const int m0 = blockIdx.y * BM, n0 = blockIdx.x * BN;
  const int wr = (wave >> 1) * (16 * FM), wc = (wave & 1) * (16 * FN);
  const int fr = lane & 15, fq = lane >> 4;
  const int rin = lane >> 4, c16 = lane & 15;
  const u16* Ws[2] = {W0, W1};
  f32x4 acc[FM][FN] = {};
  f32x4 acc2[FM][FN] = {};
  for (int k0 = 0; k0 < K; k0 += BK) {
    __syncthreads();
    #pragma unroll
    for (int c = 0; c < TOT; ++c) {
      if ((c & 3) != wave) continue;
      if (c < CA) {
        int row = c * 4 + rin;
        glds16(A + (size_t)(m0 + row) * lda + k0 + ((c16 ^ (row & 15)) * 8), &lA[c * 512]);
      } else {
        int wi = (c - CA) / CW, ch = (c - CA) % CW;
        int row = ch * 4 + rin;
        glds16(Ws[wi] + (size_t)(n0 + row) * ldw + k0 + ((c16 ^ (row & 15)) * 8),
               &lW[wi][ch * 512]);
      }
    }
    __syncthreads();
    #pragma unroll
    for (int s = 0; s < 4; ++s) {
      const int u = s * 4 + fq;
      s16x8 af[FM];
      #pragma unroll
      for (int mi = 0; mi < FM; ++mi) {
        int r = wr + mi * 16 + fr;
        af[mi] = *reinterpret_cast<const s16x8*>(&lA[r * 128 + ((u ^ (r & 15)) * 8)]);
      }
      #pragma unroll
      for (int wi = 0; wi < NWB; ++wi) {
        #pragma unroll
        for (int ni = 0; ni < FN; ++ni) {
          int r = wc + ni * 16 + fr;
          s16x8 bfr = *reinterpret_cast<const s16x8*>(&lW[wi][r * 128 + ((u ^ (r & 15)) * 8)]);
          #pragma unroll
          for (int mi = 0; mi < FM; ++mi) {
            if (MODE == 4 && wi == 1)
              acc2[mi][ni] = __builtin_amdgcn_mfma_f32_16x16x32_bf16(af[mi], bfr, acc2[mi][ni], 0, 0, 0);
            else
              acc[mi][ni] = __builtin_amdgcn_mfma_f32_16x16x32_bf16(af[mi], bfr, acc[mi][ni], 0, 0, 0);
          }
        }
      }
    }
  }
  #pragma unroll
  for (int mi = 0; mi < FM; ++mi)
    #pragma unroll
    for (int ni = 0; ni < FN; ++ni) {
      int gm = m0 + wr + mi * 16 + fq * 4;
      int gn = n0 + wc + ni * 16 + fr;
      if (MODE == 2) {
        u16* Cb = (u16*)Cv;
        #pragma unroll
        for (int r = 0; r < 4; ++r)
          Cb[(size_t)(gm + r) * ldc + gn] = f2bf(acc[mi][ni][r]);
      } else if (MODE == 4) {
        u16* Cb = (u16*)Cv;
        #pragma unroll
        for (int r = 0; r < 4; ++r) {
          float y = acc[mi][ni][r], g = acc2[mi][ni][r];
          Cb[(size_t)(gm + r) * ldc + gn] = f2bf(y * (g / (1.f + __expf(-g))));
        }
      } else if (MODE == 3) {
        u16* Cb = (u16*)Cv;
        if (gn < 1024) {
          float badd = bias[gn];
          #pragma unroll
          for (int r = 0; r < 4; ++r) {
            float s = acc[mi][ni][r] + badd;
            s = (s > 20.f) ? s : log1pf(__expf(s));
            Cb[(size_t)(gm + r) * ldc + gn] = f2bf(s);
          }
        } else if (gn < 1056) {
          #pragma unroll
          for (int r = 0; r < 4; ++r)
            aux[(size_t)(gm + r) * 32 + (gn - 1024)] = acc[mi][ni][r];
        }
      } else {
        float* C = (float*)Cv;
        float badd = (MODE == 1) ? bias[gn] : 0.f;
        #pragma unroll
        for (int r = 0; r < 4; ++r)
          C[(size_t)(gm + r) * ldc + gn] = acc[mi][ni][r] + badd;
      }
    }
}

// ---------- upfront prep; latency-bound Mext blocks FIRST, then BW-bound cvt ----------
// blocks [0,1632): Mext, 136/layer: lb<128 -> 8 dt-rows (dtw@xpw_dt); lb>=128 -> BC/pad rows.
// blocks [1632,15456): weight cvt, 1152/layer, 4096 elems/block (4 ILP chains/thread).
// blocks [15456,15520): x -> bf16.  blocks [15520,15536): emb_w -> bf16.
__global__ void k_prep(const float* __restrict__ x, const float* __restrict__ emb_w,
                       const float* __restrict__ inp_a, const float* __restrict__ outp_a,
                       const float* __restrict__ fc1_a, const float* __restrict__ fc2_a,
                       const float* __restrict__ dtw_a, const float* __restrict__ xpw_a,
                       u16* __restrict__ xb, u16* __restrict__ embh,
                       u16* __restrict__ wall) {
  int blk = blockIdx.x, tid = threadIdx.x;
  if (blk < 1632) {
    int layer = blk / 136, lb = blk % 136;
    u16* mh = wall + (size_t)layer * 5832704 + 4718592;
    const float* xpw = xpw_a + (size_t)layer * 65536;
    if (lb < 128) {
      const float* dtw = dtw_a + (size_t)layer * 32768;
      int o0 = lb * 8;
      __shared__ float lw[8][32];
      {
        int row = tid >> 5, r = tid & 31;
        lw[row][r] = dtw[(o0 + row) * 32 + r];
      }
      __syncthreads();
      f32x4 a[8] = {};
      for (int r = 0; r < 32; ++r) {
        f32x4 xv = *reinterpret_cast<const f32x4*>(xpw + (size_t)r * 1024 + tid * 4);
        #pragma unroll
        for (int row = 0; row < 8; ++row) {
          float wv = lw[row][r];
          #pragma unroll
          for (int j = 0; j < 4; ++j) a[row][j] += wv * xv[j];
        }
      }
      #pragma unroll
      for (int row = 0; row < 8; ++row) {
        u16x4 hv;
        #pragma unroll
        for (int j = 0; j < 4; ++j) hv[j] = f2bf(a[row][j]);
        *reinterpret_cast<u16x4*>(mh + (size_t)(o0 + row) * 1024 + tid * 4) = hv;
      }
    } else {
      int o0 = 1024 + (lb - 128) * 8;
      #pragma unroll
      for (int row = 0; row < 8; ++row) {
        int o = o0 + row;
        u16x4 hv = {0, 0, 0, 0};
        if (o < 1056) {
          f32x4 xv = *reinterpret_cast<const f32x4*>(xpw + (size_t)(o - 1024 + 32) * 1024 + tid * 4);
          #pragma unroll
          for (int j = 0; j < 4; ++j) hv[j] = f2bf(xv[j]);
        }
        *reinterpret_cast<u16x4*>(mh + (size_t)o * 1024 + tid * 4) = hv;
      }
    }
  } else if (blk < 15456) {
    int lb = blk - 1632;
    int layer = lb / 1152, sb = lb % 1152;
    u16* wh = wall + (size_t)layer * 5832704;
    size_t base = (size_t)sb * 4096;
    const float* s; size_t off;
    if (base < 1048576)      { s = inp_a  + (size_t)layer * 1048576; off = base; }
    else if (base < 1572864) { s = outp_a + (size_t)layer * 524288;  off = base - 1048576; }
    else if (base < 3670016) { s = fc1_a  + (size_t)layer * 2097152; off = base - 1572864; }
    else                     { s = fc2_a  + (size_t)layer * 1048576; off = base - 3670016; }
    f32x4 v[4];
    #pragma unroll
    for (int q = 0; q < 4; ++q)
      v[q] = *reinterpret_cast<const f32x4*>(s + off + q * 1024 + tid * 4);
    #pragma unroll
    for (int q = 0; q < 4; ++q) {
      u16x4 hv;
      #pragma unroll
      for (int j = 0; j < 4; ++j) hv[j] = f2bf(v[q][j]);
      *reinterpret_cast<u16x4*>(wh + base + q * 1024 + tid * 4) = hv;
    }
  } else if (blk < 15520) {
    size_t base = (size_t)(blk - 15456) * 4096;
    f32x4 v[4];
    #pragma unroll
    for (int q = 0; q < 4; ++q)
      v[q] = *reinterpret_cast<const f32x4*>(x + base + q * 1024 + tid * 4);
    #pragma unroll
    for (int q = 0; q < 4; ++q) {
      u16x4 hv;
      #pragma unroll
      for (int j = 0; j < 4; ++j) hv[j] = f2bf(v[q][j]);
      *reinterpret_cast<u16x4*>(xb + base + q * 1024 + tid * 4) = hv;
    }
  } else {
    size_t base = (size_t)(blk - 15520) * 4096;
    f32x4 v[4];
    #pragma unroll
    for (int q = 0; q < 4; ++q)
      v[q] = *reinterpret_cast<const f32x4*>(emb_w + base + q * 1024 + tid * 4);
    #pragma unroll
    for (int q = 0; q < 4; ++q) {
      u16x4 hv;
      #pragma unroll
      for (int j = 0; j < 4; ++j) hv[j] = f2bf(v[q][j]);
      *reinterpret_cast<u16x4*>(embh + base + q * 1024 + tid * 4) = hv;
    }
  }
}

// ---------- residual add + rmsnorm; zr=1 treats resid as zero (layer 0) ----------
__global__ void k_addnorm(float* __restrict__ r, const float* __restrict__ h,
                          const float* __restrict__ w, u16* __restrict__ ob, int zr) {
  int t = blockIdx.x, tid = threadIdx.x;
  size_t base = (size_t)t * 512;
  float h0 = h[base + tid], h1 = h[base + 256 + tid];
  float s0 = zr ? h0 : (r[base + tid] + h0);
  float s1 = zr ? h1 : (r[base + 256 + tid] + h1);
  float ss = s0 * s0 + s1 * s1;
  for (int m = 32; m; m >>= 1) ss += __shfl_xor(ss, m);
  __shared__ float red[4];
  if ((tid & 63) == 0) red[tid >> 6] = ss;
  __syncthreads();
  float tot = red[0] + red[1] + red[2] + red[3];
  float sc = rsqrtf(tot * (1.f / 512.f) + 1e-5f);
  r[base + tid] = s0;
  r[base + 256 + tid] = s1;
  ob[base + tid] = f2bf(s0 * sc * w[tid]);
  ob[base + 256 + tid] = f2bf(s1 * sc * w[tid + 256]);
}

// ---------- causal depthwise conv (4 taps) + silu; bf16 in, bf16 out ----------
__global__ void k_conv(const u16* __restrict__ xzb, const float* __restrict__ cw,
                       const float* __restrict__ cb, u16* __restrict__ xcb) {
  int idx = blockIdx.x * 256 + threadIdx.x;
  int t = idx >> 8, q4 = (idx & 255) * 4;
  int l = t & 511;
  f32x4 w0 = *reinterpret_cast<const f32x4*>(cw + (q4 + 0) * 4);
  f32x4 w1 = *reinterpret_cast<const f32x4*>(cw + (q4 + 1) * 4);
  f32x4 w2 = *reinterpret_cast<const f32x4*>(cw + (q4 + 2) * 4);
  f32x4 w3 = *reinterpret_cast<const f32x4*>(cw + (q4 + 3) * 4);
  f32x4 a = *reinterpret_cast<const f32x4*>(cb + q4);
  #pragma unroll
  for (int j = 0; j < 4; ++j) {
    int lj = l - 3 + j;
    if (lj >= 0) {
      u16x4 v = *reinterpret_cast<const u16x4*>(xzb + (size_t)(t - 3 + j) * 2048 + q4);
      a[0] += w0[j] * bf2f(v[0]);
      a[1] += w1[j] * bf2f(v[1]);
      a[2] += w2[j] * bf2f(v[2]);
      a[3] += w3[j] * bf2f(v[3]);
    }
  }
  u16x4 ob;
  #pragma unroll
  for (int j = 0; j < 4; ++j)
    ob[j] = f2bf(a[j] / (1.f + __expf(-a[j])));
  *reinterpret_cast<u16x4*>(xcb + (size_t)t * 1024 + q4) = ob;
}

// ---------- scan pass 1 ----------
__global__ __launch_bounds__(256) void k_scan1(
    const u16* __restrict__ dtb, const u16* __restrict__ xcb,
    const float* __restrict__ xdb, const float* __restrict__ alog,
    float* __restrict__ sP, float* __restrict__ sH) {
  int bid = blockIdx.x;
  int b = bid >> 7, dg = (bid >> 3) & 15, c = bid & 7;
  int tid = threadIdx.x, dl = tid >> 2, sq = tid & 3;
  int d = dg * 64 + dl;
  int t0 = b * 512 + c * 64;
  __shared__ u16 ldt[16][64], lxc[16][64];
  __shared__ float lB[16][16];
  f32x4 al = *reinterpret_cast<const f32x4*>(alog + (size_t)d * 16 + sq * 4);
  float A[4], h[4] = {}, P[4] = {1.f, 1.f, 1.f, 1.f};
  #pragma unroll
  for (int j = 0; j < 4; ++j) A[j] = -__expf(al[j]);
  for (int tile = 0; tile < 4; ++tile) {
    int tt = t0 + tile * 16;
    __syncthreads();
    {
      int row = tid >> 4, f4 = (tid & 15) * 4;
      *reinterpret_cast<u16x4*>(&ldt[row][f4]) =
          *reinterpret_cast<const u16x4*>(dtb + (size_t)(tt + row) * 1024 + dg * 64 + f4);
      *reinterpret_cast<u16x4*>(&lxc[row][f4]) =
          *reinterpret_cast<const u16x4*>(xcb + (size_t)(tt + row) * 1024 + dg * 64 + f4);
    }
    if (tid < 64) {
      int row = tid >> 2, f4 = (tid & 3) * 4;
      *reinterpret_cast<f32x4*>(&lB[row][f4]) =
          *reinterpret_cast<const f32x4*>(xdb + (size_t)(tt + row) * 32 + f4);
    }
    __syncthreads();
    for (int lr = 0; lr < 16; ++lr) {
      float dtv = bf2f(ldt[lr][dl]);
      float dtx = dtv * bf2f(lxc[lr][dl]);
      f32x4 Bv = *reinterpret_cast<const f32x4*>(&lB[lr][sq * 4]);
      #pragma unroll
      for (int j = 0; j < 4; ++j) {
        float e = __expf(dtv * A[j]);
        h[j] = h[j] * e + dtx * Bv[j];
        P[j] *= e;
      }
    }
  }
  size_t base = ((size_t)(c * 4 + b) * 1024 + d) * 16 + sq * 4;
  *reinterpret_cast<f32x4*>(sP + base) = (f32x4){P[0], P[1], P[2], P[3]};
  *reinterpret_cast<f32x4*>(sH + base) = (f32x4){h[0], h[1], h[2], h[3]};
}

// ---------- scan pass 2 ----------
__global__ __launch_bounds__(256) void k_scan3(
    const u16* __restrict__ dtb, const u16* __restrict__ xcb,
    const float* __restrict__ xdb, const float* __restrict__ alog,
    const float* __restrict__ sP, const float* __restrict__ sH,
    const u16* __restrict__ xzb, const float* __restrict__ Dw,
    u16* __restrict__ ygb) {
  int bid = blockIdx.x;
  int b = bid >> 7, dg = (bid >> 3) & 15, c = bid & 7;
  int tid = threadIdx.x, dl = tid >> 2, sq = tid & 3;
  int d = dg * 64 + dl;
  int t0 = b * 512 + c * 64;
  __shared__ u16 ldt[16][64], lxc[16][64];
  __shared__ float lB[16][16], lC[16][16], ly[16][64];
  f32x4 al = *reinterpret_cast<const f32x4*>(alog + (size_t)d * 16 + sq * 4);
  float A[4], h[4] = {};
  #pragma unroll
  for (int j = 0; j < 4; ++j) A[j] = -__expf(al[j]);
  {
    size_t base = ((size_t)b * 1024 + d) * 16 + sq * 4;
    for (int cc = 0; cc < c; ++cc) {
      f32x4 Pp = *reinterpret_cast<const f32x4*>(sP + (size_t)cc * 65536 + base);
      f32x4 Hh = *reinterpret_cast<const f32x4*>(sH + (size_t)cc * 65536 + base);
      #pragma unroll
      for (int j = 0; j < 4; ++j) h[j] = Pp[j] * h[j] + Hh[j];
    }
  }
  for (int tile = 0; tile < 4; ++tile) {
    int tt = t0 + tile * 16;
    __syncthreads();
    {
      int row = tid >> 4, f4 = (tid & 15) * 4;
      *reinterpret_cast<u16x4*>(&ldt[row][f4]) =
          *reinterpret_cast<const u16x4*>(dtb + (size_t)(tt + row) * 1024 + dg * 64 + f4);
      *reinterpret_cast<u16x4*>(&lxc[row][f4]) =
          *reinterpret_cast<const u16x4*>(xcb + (size_t)(tt + row) * 1024 + dg * 64 + f4);
    }
    if (tid < 64) {
      int row = tid >> 2, f4 = (tid & 3) * 4;
      *reinterpret_cast<f32x4*>(&lB[row][f4]) =
          *reinterpret_cast<const f32x4*>(xdb + (size_t)(tt + row) * 32 + f4);
    } else if (tid < 128) {
      int t2 = tid - 64;
      int row = t2 >> 2, f4 = (t2 & 3) * 4;
      *reinterpret_cast<f32x4*>(&lC[row][f4]) =
          *reinterpret_cast<const f32x4*>(xdb + (size_t)(tt + row) * 32 + 16 + f4);
    }
    __syncthreads();
    for (int lr = 0; lr < 16; ++lr) {
      float dtv = bf2f(ldt[lr][dl]);
      float dtx = dtv * bf2f(lxc[lr][dl]);
      f32x4 Bv = *reinterpret_cast<const f32x4*>(&lB[lr][sq * 4]);
      f32x4 Cv = *reinterpret_cast<const f32x4*>(&lC[lr][sq * 4]);
      float py = 0.f;
      #pragma unroll
      for (int j = 0; j < 4; ++j) {
        float e = __expf(dtv * A[j]);
        h[j] = h[j] * e + dtx * Bv[j];
        py += h[j] * Cv[j];
      }
      py += __shfl_xor(py, 1);
      py += __shfl_xor(py, 2);
      if (sq == 0) ly[lr][dl] = py;
    }
    __syncthreads();
    {
      int row = tid >> 4, f4 = (tid & 15) * 4;
      f32x4 y4 = *reinterpret_cast<f32x4*>(&ly[row][f4]);
      u16x4 x4 = *reinterpret_cast<u16x4*>(&lxc[row][f4]);
      u16x4 z4 = *reinterpret_cast<const u16x4*>(xzb + (size_t)(tt + row) * 2048 + 1024 + dg * 64 + f4);
      f32x4 D4 = *reinterpret_cast<const f32x4*>(Dw + dg * 64 + f4);
      u16x4 o;
      #pragma unroll
      for (int j = 0; j < 4; ++j) {
        float yv = y4[j] + bf2f(x4[j]) * D4[j];
        float zz = bf2f(z4[j]);
        float g = zz / (1.f + __expf(-zz));
        o[j] = f2bf(yv * g);
      }
      *reinterpret_cast<u16x4*>(ygb + (size_t)(tt + row) * 1024 + dg * 64 + f4) = o;
    }
  }
}

// ---------- mean pool (bf16 in) + head ----------
__global__ void k_pool(const u16* __restrict__ xnb, float* __restrict__ pooled) {
  int b = blockIdx.x >> 1, half = blockIdx.x & 1;
  int tid = threadIdx.x;
  int dm = half * 256 + tid;
  float s = 0.f;
  for (int l = 0; l < 512; ++l)
    s += bf2f(xnb[(size_t)(b * 512 + l) * 512 + dm]);
  pooled[b * 512 + dm] = s * (1.f / 512.f);
}

__global__ void k_head(const float* __restrict__ pooled, const float* __restrict__ hw,
                       const float* __restrict__ hb, float* __restrict__ out) {
  int b = blockIdx.x / 50, c = blockIdx.x % 50;
  int lane = threadIdx.x;
  float s = 0.f;
  #pragma unroll
  for (int q = 0; q < 8; ++q) {
    int dm = q * 64 + lane;
    s += pooled[b * 512 + dm] * hw[(size_t)c * 512 + dm];
  }
  for (int m = 32; m; m >>= 1) s += __shfl_xor(s, m);
  if (lane == 0) out[b * 50 + c] = s + hb[c];
}

// ---------- launch ----------
extern "C" void kernel_launch(void* const* d_in, const int* in_sizes, int n_in,
                              void* d_out, int out_size, void* d_ws, size_t ws_size,
                              hipStream_t stream) {
  (void)in_sizes; (void)n_in; (void)out_size; (void)ws_size;
  const float* x      = (const float*)d_in[0];
  const float* emb_w  = (const float*)d_in[1];
  const float* emb_b  = (const float*)d_in[2];
  const float* inp_w  = (const float*)d_in[3];
  const float* conv_w = (const float*)d_in[4];
  const float* conv_b = (const float*)d_in[5];
  const float* xp_w   = (const float*)d_in[6];
  const float* dt_w   = (const float*)d_in[7];
  const float* dt_b   = (const float*)d_in[8];
  const float* a_log  = (const float*)d_in[9];
  const float* Dw     = (const float*)d_in[10];
  const float* outp_w = (const float*)d_in[11];
  const float* n1_w   = (const float*)d_in[12];
  const float* n2_w   = (const float*)d_in[13];
  const float* fc1_w  = (const float*)d_in[14];
  const float* fc2_w  = (const float*)d_in[15];
  const float* nf_w   = (const float*)d_in[16];
  const float* head_w = (const float*)d_in[17];
  const float* head_b = (const float*)d_in[18];

  float* fp = (float*)d_ws;
  float* resid  = fp;                 // 2048 x 512
  float* hid    = fp + 1048576;
  float* xdb    = fp + 2097152;       // T x 32 (B|C)
  float* sP     = fp + 2162688;       // 8 x 4 x 1024 x 16
  float* sH     = fp + 2686976;
  float* pooled = fp + 3211264;       // 2048
  u16* us  = (u16*)(fp + 3213312);
  u16* xzb  = us;                     // T x 2048
  u16* xb   = us + 4194304;           // 262144
  u16* xnb  = us + 4456448;           // T x 512
  u16* ygb  = us + 5505024;           // T x 1024
  u16* mlb  = us + 7602176;           // T x 2048
  u16* xcb  = us + 11796480;          // T x 1024
  u16* dtb  = us + 13893632;          // T x 1024
  u16* embh = us + 15990784;          // 512 x 128
  u16* wall = us + 16056320;          // 12 x (inp|outp|fc1|fc2|Mext) = 12 x 5,832,704

  const int O_OUTP = 1048576, O_FC1 = 1572864, O_FC2 = 3670016, O_M = 4718592;
  const size_t WSTRIDE = 5832704;

  k_prep<<<15536, 256, 0, stream>>>(x, emb_w, inp_w, outp_w, fc1_w, fc2_w, dt_w, xp_w,
                                    xb, embh, wall);
  gemm_bf<2, 1, 1, 1><<<dim3(16, 32), 256, 0, stream>>>(
      xb, 128, embh, nullptr, 128, (void*)hid, 512, 128, emb_b, nullptr);

  for (int i = 0; i < 12; ++i) {
    const u16* wL = wall + (size_t)i * WSTRIDE;
    k_addnorm<<<2048, 256, 0, stream>>>(resid, hid, n1_w + i * 512, xnb, i == 0 ? 1 : 0);
    gemm_bf<4, 2, 1, 2><<<dim3(32, 16), 256, 0, stream>>>(
        xnb, 512, wL, nullptr, 512, (void*)xzb, 2048, 512, nullptr, nullptr);
    k_conv<<<2048, 256, 0, stream>>>(xzb, conv_w + (size_t)i * 4096, conv_b + i * 1024, xcb);
    gemm_bf<2, 2, 1, 3><<<dim3(17, 32), 256, 0, stream>>>(
        xcb, 1024, wL + O_M, nullptr, 1024, (void*)dtb, 1024, 1024, dt_b + i * 1024, xdb);
    k_scan1<<<512, 256, 0, stream>>>(dtb, xcb, xdb, a_log + (size_t)i * 16384, sP, sH);
    k_scan3<<<512, 256, 0, stream>>>(dtb, xcb, xdb, a_log + (size_t)i * 16384, sP, sH,
                                     xzb, Dw + i * 1024, ygb);
    gemm_bf<2, 1, 1, 0><<<dim3(16, 32), 256, 0, stream>>>(
        ygb, 1024, wL + O_OUTP, nullptr, 1024, (void*)hid, 512, 1024, nullptr, nullptr);
    k_addnorm<<<2048, 256, 0, stream>>>(resid, hid, n2_w + i * 512, xnb, 0);
    gemm_bf<4, 2, 2, 4><<<dim3(32, 16), 256, 0, stream>>>(
        xnb, 512, wL + O_FC1, wL + O_FC1 + 1048576, 512,
        (void*)mlb, 2048, 512, nullptr, nullptr);
    gemm_bf<2, 1, 1, 0><<<dim3(16, 32), 256, 0, stream>>>(
        mlb, 2048, wL + O_FC2, nullptr, 2048, (void*)hid, 512, 2048, nullptr, nullptr);
  }

  k_addnorm<<<2048, 256, 0, stream>>>(resid, hid, nf_w, xnb, 0);
  k_pool<<<8, 256, 0, stream>>>(xnb, pooled);
  k_head<<<200, 64, 0, stream>>>(pooled, head_w, head_b, (float*)d_out);
}